// Round 13
// baseline (209.232 us; speedup 1.0000x reference)
//
#include <hip/hip_runtime.h>
#include <hip/hip_bf16.h>

// B=2, N=2048, E=1024, H=16, HD=64. Inputs fp32, output fp32.
// ws (32 MiB): kbuf qbuf vbuf sabuf (bf16, 8 MB each).
// Scratch plan:
//   xbf    (8 MB)  -> d_out[0..8M),  dead after qkv_mfma
//   vtb    (8 MB)  -> d_out[8..16M), V^T [bh][d][n] written BY qkv epilogue,
//                     dead after attn2
//   p0     (8 MB)  -> d_out[0..8M)  (attn2 partial 0, dead after merge)
//   p1     (8 MB)  -> vbuf (partial 1; merge overwrites in place with sa)
//   wqkv_t (6 MB)  -> sabuf[0..3M elems), dead after qkv_mfma
//   wout_t (2 MB)  -> sabuf[3M..4M elems)  (written in prep, read by out)
//   m/l    (1 MB)  -> sabuf head (inside dead wqkv_t region during attn2)
// Q is PRE-SCALED by 0.125*log2(e); attn2 softmax runs in log2 domain.
#define Bz 2
#define Nn 2048
#define Ee 1024
#define Hh 16
#define HD 64

typedef unsigned short u16;
typedef unsigned int u32;

typedef __bf16 bf16x8 __attribute__((ext_vector_type(8)));
typedef float f32x4 __attribute__((ext_vector_type(4)));

#define QK_SCALE 0.18033688f  // 0.125 * log2(e)

__device__ __forceinline__ float bf2f(u16 u) {
    u32 v = ((u32)u) << 16;
    return __builtin_bit_cast(float, v);
}
__device__ __forceinline__ u16 f2bf(float f) {
    u32 i = __builtin_bit_cast(u32, f);
    u32 r = (i + 0x7FFFu + ((i >> 16) & 1u)) >> 16;  // RNE
    return (u16)r;
}
__device__ __forceinline__ u32 pack2(float a, float b) {
    return (u32)f2bf(a) | ((u32)f2bf(b) << 16);
}
// cheap bf16 pair pack via v_perm, round-half-up (P in [0,1], no overflow)
__device__ __forceinline__ u32 pack2p(float a, float b) {
    u32 ua = __builtin_bit_cast(u32, a) + 0x8000u;
    u32 ub = __builtin_bit_cast(u32, b) + 0x8000u;
    return __builtin_amdgcn_perm(ub, ua, 0x07060302u);
}
__device__ __forceinline__ bf16x8 ld_frag(const u16* p) {
    return __builtin_bit_cast(bf16x8, *(const uint4*)p);
}
__device__ __forceinline__ f32x4 zero4() {
    f32x4 z; z[0]=0.f; z[1]=0.f; z[2]=0.f; z[3]=0.f; return z;
}

// async 16B/lane global->LDS DMA; LDS dest = (uniform base) + lane*16.
__device__ __forceinline__ void async_copy16(const u16* g, u16* l) {
    __builtin_amdgcn_global_load_lds(
        (const __attribute__((address_space(1))) u32*)g,
        (__attribute__((address_space(3))) u32*)l, 16, 0, 0);
}

__global__ void ws_diag(float* out, float code) { out[0] = code; }

// ---------------------------------------------------------------------------
// prep: fused preprocessing, 3072 blocks.
//   id <  2048: x fp32 -> bf16 row-major (xbf)
//   id <  2816: Wqkv [h][1024k][192n] f32 -> wqkv_t [h][192n][1024k] bf16
//   else      : Wout [1024k][1024n] f32 -> wout_t [1024n][1024k] bf16
// ---------------------------------------------------------------------------
__global__ __launch_bounds__(256) void prep(
    const float* __restrict__ x, u16* __restrict__ xbf,
    const float* __restrict__ Wqkv, u16* __restrict__ wqkv_t,
    const float* __restrict__ Wout, u16* __restrict__ wout_t)
{
    const int id = blockIdx.x;
    const int tid = threadIdx.x;
    __shared__ float T[64][65];

    if (id < 2048) {
        size_t idx = ((size_t)id * 256 + tid) * 8;
        float4 f0 = *(const float4*)(x + idx);
        float4 f1 = *(const float4*)(x + idx + 4);
        uint4 pk;
        pk.x = pack2(f0.x, f0.y); pk.y = pack2(f0.z, f0.w);
        pk.z = pack2(f1.x, f1.y); pk.w = pack2(f1.z, f1.w);
        *(uint4*)(xbf + idx) = pk;
        return;
    }

    const float* src; u16* dst; int R, C, r0, c0;
    if (id < 2816) {
        int j = id - 2048;
        R = 1024; C = 192;
        r0 = (j & 15) * 64; c0 = ((j >> 4) % 3) * 64;
        size_t zoff = (size_t)(j / 48) * R * C;
        src = Wqkv + zoff; dst = wqkv_t + zoff;
    } else {
        int j = id - 2816;
        R = 1024; C = 1024;
        r0 = (j & 15) * 64; c0 = (j >> 4) * 64;
        src = Wout; dst = wout_t;
    }
    {
        int tr = tid >> 2, tc = (tid & 3) * 16;
        const float* s = src + (size_t)(r0 + tr) * C + c0 + tc;
#pragma unroll
        for (int j = 0; j < 4; ++j) {
            float4 v = ((const float4*)s)[j];
            T[tr][tc + 4 * j + 0] = v.x; T[tr][tc + 4 * j + 1] = v.y;
            T[tr][tc + 4 * j + 2] = v.z; T[tr][tc + 4 * j + 3] = v.w;
        }
    }
    __syncthreads();
    {
        int cc = tid >> 2, rr = (tid & 3) * 16;
        u16* d = dst + (size_t)(c0 + cc) * R + r0 + rr;
        u32 w[8];
#pragma unroll
        for (int i = 0; i < 8; ++i)
            w[i] = pack2(T[rr + 2 * i][cc], T[rr + 2 * i + 1][cc]);
        *(uint4*)(d)     = make_uint4(w[0], w[1], w[2], w[3]);
        *(uint4*)(d + 8) = make_uint4(w[4], w[5], w[6], w[7]);
    }
}

// ---------------------------------------------------------------------------
// Kernel 1: QKV projection, MFMA 16x16x32, async staging.
// Block 128m x 192n (one head), grid (32,16). Q pre-scaled by QK_SCALE.
// K,Q written [bh][n][d]; V written TRANSPOSED into vtb [bh][d][n]
// (4 consecutive tokens per lane -> ushort4; replaces transpose_v kernel).
// ---------------------------------------------------------------------------
__global__ __launch_bounds__(256) void qkv_mfma(
    const u16* __restrict__ xbf, const u16* __restrict__ Wt,
    const float* __restrict__ bias,
    u16* __restrict__ kbuf, u16* __restrict__ qbuf, u16* __restrict__ vtb)
{
    const int mt = blockIdx.x;   // 0..31
    const int h  = blockIdx.y;   // 0..15
    const int tid = threadIdx.x;
    const int lane = tid & 63, wid = tid >> 6;
    const int wy = wid >> 1, wx = wid & 1;
    const int quad = lane >> 4, l15 = lane & 15;

    __shared__ u16 As[128 * 64];   // [m][8 chunks of 8], swizzled
    __shared__ u16 Bs[192 * 64];   // [n][8 chunks], swizzled

    f32x4 acc[4][6];
#pragma unroll
    for (int mi = 0; mi < 4; ++mi)
#pragma unroll
        for (int ni = 0; ni < 6; ++ni) acc[mi][ni] = zero4();

    const u16* xb = xbf + (size_t)mt * 128 * Ee;
    const u16* wtb = Wt + (size_t)h * 192 * 1024;

    const int arowl = lane >> 3;
    const int jj = (lane & 7) ^ arowl;

    for (int kb = 0; kb < 16; ++kb) {
        __syncthreads();
#pragma unroll
        for (int i = 0; i < 4; ++i) {
            int rbase = (wid * 4 + i) * 8;
            const u16* g = xb + (size_t)(rbase + arowl) * Ee + kb * 64 + jj * 8;
            async_copy16(g, &As[(wid * 4 + i) * 512]);
        }
#pragma unroll
        for (int i = 0; i < 6; ++i) {
            int rbase = (wid * 6 + i) * 8;
            const u16* g = wtb + (size_t)(rbase + arowl) * 1024 + kb * 64 + jj * 8;
            async_copy16(g, &Bs[(wid * 6 + i) * 512]);
        }
        __syncthreads();

#pragma unroll
        for (int kk0 = 0; kk0 < 2; ++kk0) {
            const int pos = ((kk0 * 4 + quad) ^ (l15 & 7)) * 8;
            bf16x8 af[4], bf[6];
#pragma unroll
            for (int mi = 0; mi < 4; ++mi)
                af[mi] = ld_frag(&As[(wy * 64 + mi * 16 + l15) * 64 + pos]);
#pragma unroll
            for (int ni = 0; ni < 6; ++ni)
                bf[ni] = ld_frag(&Bs[(wx * 96 + ni * 16 + l15) * 64 + pos]);
#pragma unroll
            for (int mi = 0; mi < 4; ++mi)
#pragma unroll
                for (int ni = 0; ni < 6; ++ni)
                    acc[mi][ni] = __builtin_amdgcn_mfma_f32_16x16x32_bf16(
                        af[mi], bf[ni], acc[mi][ni], 0, 0, 0);
        }
    }

    // epilogue: cols 0..63 K, 64..127 Q (pre-scaled), 128..191 V (transposed)
#pragma unroll
    for (int ni = 0; ni < 6; ++ni) {
        int col = wx * 96 + ni * 16 + l15;   // 0..191
        int ft = col >> 6, d = col & 63;
        float sc = (ft == 1) ? QK_SCALE : 1.0f;
        float bv = bias[h * 192 + col];
#pragma unroll
        for (int mi = 0; mi < 4; ++mi) {
            int gmb = mt * 128 + wy * 64 + mi * 16 + quad * 4;
            int bb = gmb >> 11, n = gmb & (Nn - 1);
            if (ft == 2) {
                ushort4 ov;
                ov.x = f2bf(acc[mi][ni][0] + bv);
                ov.y = f2bf(acc[mi][ni][1] + bv);
                ov.z = f2bf(acc[mi][ni][2] + bv);
                ov.w = f2bf(acc[mi][ni][3] + bv);
                *(ushort4*)&vtb[((size_t)(bb * Hh + h) * HD + d) * Nn + n] = ov;
            } else {
                u16* dst = (ft == 0) ? kbuf : qbuf;
#pragma unroll
                for (int r = 0; r < 4; ++r)
                    dst[(((size_t)(bb * Hh + h)) * Nn + (n + r)) * HD + d] =
                        f2bf((acc[mi][ni][r] + bv) * sc);
            }
        }
    }
}

// ---------------------------------------------------------------------------
// Kernel 2: split-K causal flash attention, transposed-S, MFMA 16x16x32.
// (R12 structure; pack via v_perm.)
// ---------------------------------------------------------------------------
__global__ __launch_bounds__(256) void attn2(
    const u16* __restrict__ qbuf, const u16* __restrict__ kbuf,
    const u16* __restrict__ vtb, u16* __restrict__ p0buf,
    u16* __restrict__ p1buf, float* __restrict__ ml)
{
    const int id = blockIdx.x;                      // 0..1023
    const int bh = (id & 7) * 4 + ((id >> 3) & 3);  // 4 bh per XCD
    const int p  = id >> 5;                         // 0..31
    const int tid = threadIdx.x;
    const int lane = tid & 63, wid = tid >> 6;
    const int l15 = lane & 15, quad = lane >> 4;

    __shared__ u16 KsL[2][4096];   // [buf][key 64][d 64] chunk-swizzled
    __shared__ u16 VtL[2][4096];   // [buf][d 64][key 64] chunk-swizzled

    const u16* qb = qbuf + (size_t)bh * Nn * HD;
    const u16* kb = kbuf + (size_t)bh * Nn * HD;
    const u16* vt = vtb + (size_t)bh * HD * Nn;

    const int r_l = lane >> 3;
    const int jj = (lane & 7) ^ r_l;
    const int xsw = l15 & 7;
    const int src0 = l15 + (quad & 1) * 32;
    const bool qhi = quad >= 2;

    for (int sg = 0; sg < 2; ++sg) {
        const int qt = sg ? (31 - p) : p;
        const int T  = qt + 1;
        const int t0 = sg ? ((T + 1) >> 1) : 0;
        const int t1 = sg ? T : ((p + 2) >> 1);
        u16*   pb = sg ? p1buf : p0buf;
        float* mb = ml + (sg ? 131072 : 0);
        float* lb = ml + (sg ? 196608 : 65536);

        const int qrow = qt * 64 + wid * 16 + l15;

        f32x4 oacc[4];
#pragma unroll
        for (int dt = 0; dt < 4; ++dt) oacc[dt] = zero4();
        float m_i = -3e38f, l_i = 0.f;

        if (t0 < t1) {
            bf16x8 qf[2];
#pragma unroll
            for (int st = 0; st < 2; ++st)
                qf[st] = __builtin_bit_cast(bf16x8,
                    *(const uint4*)(qb + (size_t)qrow * HD + st * 32 + quad * 8));

            __syncthreads();
#pragma unroll
            for (int i2 = 0; i2 < 4; ++i2) {
                int idx = wid * 4 + i2;
                if (idx < 8) {
                    const u16* g = kb + (size_t)(t0 * 64 + idx * 8 + r_l) * HD + jj * 8;
                    async_copy16(g, &KsL[0][idx * 512]);
                } else {
                    int ii = idx - 8;
                    const u16* g = vt + (size_t)(ii * 8 + r_l) * Nn + t0 * 64 + jj * 8;
                    async_copy16(g, &VtL[0][ii * 512]);
                }
            }

            const int nit = t1 - t0;
            for (int i = 0; i < nit; ++i) {
                const int tk = t0 + i;
                __syncthreads();  // drains DMA for buf[i&1]; fences prev reads
                if (i + 1 < nit) {
                    const int nb = (i + 1) & 1;
#pragma unroll
                    for (int i2 = 0; i2 < 4; ++i2) {
                        int idx = wid * 4 + i2;
                        if (idx < 8) {
                            const u16* g = kb + (size_t)((tk + 1) * 64 + idx * 8 + r_l) * HD + jj * 8;
                            async_copy16(g, &KsL[nb][idx * 512]);
                        } else {
                            int ii = idx - 8;
                            const u16* g = vt + (size_t)(ii * 8 + r_l) * Nn + (tk + 1) * 64 + jj * 8;
                            async_copy16(g, &VtL[nb][ii * 512]);
                        }
                    }
                }
                const u16* K = KsL[i & 1];
                const u16* V = VtL[i & 1];

                f32x4 s[4];
#pragma unroll
                for (int t = 0; t < 4; ++t) {
                    f32x4 a = zero4();
#pragma unroll
                    for (int st = 0; st < 2; ++st) {
                        bf16x8 kf = ld_frag(&K[(t * 16 + l15) * 64 +
                                               ((st * 4 + quad) ^ xsw) * 8]);
                        a = __builtin_amdgcn_mfma_f32_16x16x32_bf16(kf, qf[st], a, 0, 0, 0);
                    }
                    s[t] = a;
                }

                if (tk == qt) {
#pragma unroll
                    for (int t = 0; t < 4; ++t)
#pragma unroll
                        for (int r = 0; r < 4; ++r) {
                            int key = tk * 64 + t * 16 + quad * 4 + r;
                            if (key > qrow) s[t][r] = -3e38f;
                        }
                }

                float mx = s[0][0];
#pragma unroll
                for (int t = 0; t < 4; ++t)
#pragma unroll
                    for (int r = 0; r < 4; ++r) mx = fmaxf(mx, s[t][r]);
                mx = fmaxf(mx, __shfl_xor(mx, 16));
                mx = fmaxf(mx, __shfl_xor(mx, 32));
                float mn = fmaxf(m_i, mx);
                float alpha = exp2f(m_i - mn);
                m_i = mn;
                float rs = 0.f;
#pragma unroll
                for (int t = 0; t < 4; ++t)
#pragma unroll
                    for (int r = 0; r < 4; ++r) {
                        float e = exp2f(s[t][r] - mn);
                        s[t][r] = e;
                        rs += e;
                    }
                rs += __shfl_xor(rs, 16);
                rs += __shfl_xor(rs, 32);
                l_i = l_i * alpha + rs;
#pragma unroll
                for (int dt = 0; dt < 4; ++dt)
#pragma unroll
                    for (int r = 0; r < 4; ++r) oacc[dt][r] *= alpha;

                u32 pk[4][2];
#pragma unroll
                for (int t = 0; t < 4; ++t) {
                    pk[t][0] = pack2p(s[t][0], s[t][1]);
                    pk[t][1] = pack2p(s[t][2], s[t][3]);
                }
#pragma unroll
                for (int st = 0; st < 2; ++st) {
                    u32 e0 = pk[2 * st][0],     e1 = pk[2 * st][1];
                    u32 o0 = pk[2 * st + 1][0], o1 = pk[2 * st + 1][1];
                    u32 A0 = __shfl(e0, src0),      B0 = __shfl(o0, src0);
                    u32 A1 = __shfl(e1, src0),      B1 = __shfl(o1, src0);
                    u32 A2 = __shfl(e0, src0 + 16), B2 = __shfl(o0, src0 + 16);
                    u32 A3 = __shfl(e1, src0 + 16), B3 = __shfl(o1, src0 + 16);
                    u32 U0 = qhi ? B0 : A0;
                    u32 U1 = qhi ? B1 : A1;
                    u32 U2 = qhi ? B2 : A2;
                    u32 U3 = qhi ? B3 : A3;
                    bf16x8 pf = __builtin_bit_cast(bf16x8, make_uint4(U0, U1, U2, U3));
#pragma unroll
                    for (int dt = 0; dt < 4; ++dt) {
                        bf16x8 vf = ld_frag(&V[(dt * 16 + l15) * 64 +
                                               ((st * 4 + quad) ^ xsw) * 8]);
                        oacc[dt] = __builtin_amdgcn_mfma_f32_16x16x32_bf16(
                            vf, pf, oacc[dt], 0, 0, 0);
                    }
                }
            }
        }

#pragma unroll
        for (int dt = 0; dt < 4; ++dt) {
            ushort4 ov;
            ov.x = f2bf(oacc[dt][0]);
            ov.y = f2bf(oacc[dt][1]);
            ov.z = f2bf(oacc[dt][2]);
            ov.w = f2bf(oacc[dt][3]);
            *(ushort4*)&pb[((size_t)bh * Nn + qrow) * HD + dt * 16 + quad * 4] = ov;
        }
        if (quad == 0) {
            mb[bh * Nn + qrow] = m_i;
            lb[bh * Nn + qrow] = l_i;
        }
    }
}

// ---------------------------------------------------------------------------
// Merge: sa = (a1*p0 + a2*p1) / (a1*l1 + a2*l2); writes in place over p1.
// ---------------------------------------------------------------------------
__global__ __launch_bounds__(256) void attn_merge(
    const u16* __restrict__ p0, u16* __restrict__ p1,
    const float* __restrict__ ml)
{
    const int idx = blockIdx.x * 256 + threadIdx.x;  // 0..524287
    const int row = idx >> 3;                        // bh*2048+n
    const int dc = (idx & 7) * 8;

    const float m1 = ml[row],          l1 = ml[65536 + row];
    const float m2 = ml[131072 + row], l2 = ml[196608 + row];
    const float m = fmaxf(m1, m2);
    const float a1 = exp2f(m1 - m), a2 = exp2f(m2 - m);
    const float inv = 1.f / (a1 * l1 + a2 * l2);
    const float s1 = a1 * inv, s2 = a2 * inv;

    const size_t off = (size_t)row * HD + dc;
    uint4 v0 = *(const uint4*)&p0[off];
    uint4 v1 = *(const uint4*)&p1[off];
    u32 a[4] = {v0.x, v0.y, v0.z, v0.w};
    u32 b[4] = {v1.x, v1.y, v1.z, v1.w};
    u32 w[4];
#pragma unroll
    for (int j = 0; j < 4; ++j) {
        float x0 = bf2f((u16)a[j]) * s1 + bf2f((u16)b[j]) * s2;
        float x1 = bf2f((u16)(a[j] >> 16)) * s1 + bf2f((u16)(b[j] >> 16)) * s2;
        w[j] = pack2(x0, x1);
    }
    *(uint4*)&p1[off] = make_uint4(w[0], w[1], w[2], w[3]);
}

// ---------------------------------------------------------------------------
// Kernel 3 v2: output projection, MFMA 32x32x16, async DMA staging.
// A (sa) in [bh][n][d]: the k-tile of 64 = exactly head kb -> DMA-able rows.
// ---------------------------------------------------------------------------
typedef float f32x16 __attribute__((ext_vector_type(16)));
__device__ __forceinline__ f32x16 zero16() {
    f32x16 z;
#pragma unroll
    for (int i = 0; i < 16; ++i) z[i] = 0.f;
    return z;
}

__global__ __launch_bounds__(256) void out_mfma(
    const u16* __restrict__ A, const u16* __restrict__ Wt,
    const float* __restrict__ bias, float* __restrict__ out)
{
    const int mt = blockIdx.x;  // 0..31
    const int nt = blockIdx.y;  // 0..15
    const int tid = threadIdx.x;
    const int lane = tid & 63, wid = tid >> 6;
    const int l31 = lane & 31, half = lane >> 5;

    __shared__ u16 As[128 * 64];   // swizzled chunks
    __shared__ u16 Bs[64 * 64];

    f32x16 acc[2];
    acc[0] = zero16(); acc[1] = zero16();

    const int r_l = lane >> 3;
    const int jj = (lane & 7) ^ r_l;

    for (int kb = 0; kb < 16; ++kb) {
        __syncthreads();
        // A: 128 rows x 64 k; head h = kb
#pragma unroll
        for (int i = 0; i < 4; ++i) {
            int row = (wid * 4 + i) * 8 + r_l;       // 0..127
            int gm = mt * 128 + row;
            int bb = gm >> 11, n = gm & (Nn - 1);
            const u16* g = A + ((size_t)(bb * Hh + kb) * Nn + n) * HD + jj * 8;
            async_copy16(g, &As[(wid * 4 + i) * 512]);
        }
        // B: 64 rows x 64 k
#pragma unroll
        for (int i = 0; i < 2; ++i) {
            int row = (wid * 2 + i) * 8 + r_l;       // 0..63
            const u16* g = Wt + (size_t)(nt * 64 + row) * 1024 + kb * 64 + jj * 8;
            async_copy16(g, &Bs[(wid * 2 + i) * 512]);
        }
        __syncthreads();
#pragma unroll
        for (int kc = 0; kc < 4; ++kc) {
            const int pa = ((kc * 2 + half) ^ (l31 & 7)) * 8;
            bf16x8 af = ld_frag(&As[(wid * 32 + l31) * 64 + pa]);
#pragma unroll
            for (int ct = 0; ct < 2; ++ct) {
                bf16x8 bf = ld_frag(&Bs[(ct * 32 + l31) * 64 + pa]);
                acc[ct] = __builtin_amdgcn_mfma_f32_32x32x16_bf16(af, bf, acc[ct], 0, 0, 0);
            }
        }
    }

#pragma unroll
    for (int ct = 0; ct < 2; ++ct) {
        int col = nt * 64 + ct * 32 + l31;
        float bv = bias[col];
#pragma unroll
        for (int r = 0; r < 16; ++r) {
            int row_l = (r & 3) + 8 * (r >> 2) + 4 * half;
            int gm2 = mt * 128 + wid * 32 + row_l;
            out[(size_t)gm2 * Ee + col] = acc[ct][r] + bv;
        }
    }
}

// ---------------------------------------------------------------------------
extern "C" void kernel_launch(void* const* d_in, const int* in_sizes, int n_in,
                              void* d_out, int out_size, void* d_ws, size_t ws_size,
                              hipStream_t stream) {
    const float* x    = (const float*)d_in[0];  // [2,2048,1024] f32
    const float* Wqkv = (const float*)d_in[1];  // [16,1024,192] f32
    const float* bqkv = (const float*)d_in[2];  // [16,192] f32
    const float* Wout = (const float*)d_in[3];  // [1024,1024] f32
    const float* bout = (const float*)d_in[4];  // [1024] f32
    float* out = (float*)d_out;                 // [2,2048,1024] f32

    const size_t SZ = (size_t)Bz * Hh * Nn * HD;        // 4,194,304 elems
    const size_t NSA = (size_t)Bz * Nn * Ee;            // 4,194,304 elems
    const size_t NEED = (3 * SZ + NSA) * sizeof(u16);   // 32 MiB

    if (ws_size < NEED) {
        ws_diag<<<1, 1, 0, stream>>>(out, 20000.0f + (float)(ws_size >> 20));
        return;
    }

    u16* ws = (u16*)d_ws;
    u16* kbuf  = ws;
    u16* qbuf  = ws + SZ;
    u16* vbuf  = ws + 2 * SZ;
    u16* sabuf = ws + 3 * SZ;
    u16* wqkv_t = sabuf;                      // 3,145,728 elems (6 MB)
    u16* wout_t = sabuf + 16 * 192 * 1024;    // 1,048,576 elems (2 MB)
    u16* xbf    = (u16*)d_out;                // 8 MB scratch (dead after qkv)
    u16* vtb    = (u16*)d_out + SZ;           // V^T [bh][d][n] (dead after attn2)
    u16* p0     = (u16*)d_out;                // partial 0 (over dead xbf)
    u16* p1     = vbuf;                       // partial 1; merge -> final sa
    float* ml   = (float*)sabuf;              // 1 MB (inside dead wqkv_t)

    prep<<<dim3(3072), 256, 0, stream>>>(x, xbf, Wqkv, wqkv_t, Wout, wout_t);
    qkv_mfma<<<dim3(32, 16), 256, 0, stream>>>(xbf, wqkv_t, bqkv, kbuf, qbuf, vtb);
    attn2<<<dim3(1024), 256, 0, stream>>>(qbuf, kbuf, vtb, p0, p1, ml);
    attn_merge<<<dim3(2048), 256, 0, stream>>>(p0, p1, ml);
    out_mfma<<<dim3(32, 16), 256, 0, stream>>>(p1, wout_t, bout, out);
}